// Round 2
// baseline (9.862 us; speedup 1.0000x reference)
//
#include <hip/hip_runtime.h>
#include <float.h>

#define B 64
#define S 512
#define H 1024

// One block per (batch, entity). 256 threads.
// Phase 1: scan the S=512 tokens (int2 loads, 2 tokens/thread) for
//   ids == 997+e && mask != 0; append matches to an LDS list.
// Phase 2: each thread owns one float4 chunk of the H=1024 pooled vector
//   (H/4 == 256 == blockDim), max-reduces over the (tiny) match list, and
//   stores it to both destination slots in the (B,3,2H) output.
__global__ __launch_bounds__(256) void entity_pool_kernel(
    const float* __restrict__ hidden,   // (B,S,H) f32
    const int*   __restrict__ ids,      // (B,S) i32
    const int*   __restrict__ amask,    // (B,S) i32
    float*       __restrict__ out)      // (B,3,2H) f32
{
    const int b   = blockIdx.x;   // 0..B-1
    const int e   = blockIdx.y;   // 0..2
    const int tid = threadIdx.x;  // 0..255

    __shared__ int match_pos[S];
    __shared__ int match_cnt;
    if (tid == 0) match_cnt = 0;
    __syncthreads();

    // ---- Phase 1: scan (2 consecutive tokens per thread via int2) ----
    {
        const int2 id2 = ((const int2*)(ids   + b * S))[tid];
        const int2 am2 = ((const int2*)(amask + b * S))[tid];
        const int target = 997 + e;
        if (id2.x == target && am2.x != 0) {
            int slot = atomicAdd(&match_cnt, 1);
            match_pos[slot] = 2 * tid;
        }
        if (id2.y == target && am2.y != 0) {
            int slot = atomicAdd(&match_cnt, 1);
            match_pos[slot] = 2 * tid + 1;
        }
    }
    __syncthreads();

    const int cnt = match_cnt;

    // destination mapping for pooled[b, e, :]:
    //   e=0 (p0): out[b][0][0:H],  out[b][1][0:H]
    //   e=1 (p1): out[b][0][H:2H], out[b][2][0:H]
    //   e=2 (p2): out[b][1][H:2H], out[b][2][H:2H]
    int j0, half0, j1, half1;
    if (e == 0)      { j0 = 0; half0 = 0; j1 = 1; half1 = 0; }
    else if (e == 1) { j0 = 0; half0 = 1; j1 = 2; half1 = 0; }
    else             { j0 = 1; half0 = 1; j1 = 2; half1 = 1; }

    const long out_base = (long)b * 3 * (2 * H);
    float4* dst0 = (float4*)(out + out_base + (long)j0 * (2 * H) + half0 * H);
    float4* dst1 = (float4*)(out + out_base + (long)j1 * (2 * H) + half1 * H);

    // ---- Phase 2: one float4 per thread ----
    const float4* hb4 = (const float4*)(hidden + (long)b * S * H);

    float4 v = make_float4(0.f, 0.f, 0.f, 0.f);
    if (cnt > 0) {
        v = make_float4(-FLT_MAX, -FLT_MAX, -FLT_MAX, -FLT_MAX);
        for (int i = 0; i < cnt; ++i) {
            const float4 r = hb4[match_pos[i] * (H / 4) + tid];
            v.x = fmaxf(v.x, r.x);
            v.y = fmaxf(v.y, r.y);
            v.z = fmaxf(v.z, r.z);
            v.w = fmaxf(v.w, r.w);
        }
    }
    dst0[tid] = v;
    dst1[tid] = v;
}

extern "C" void kernel_launch(void* const* d_in, const int* in_sizes, int n_in,
                              void* d_out, int out_size, void* d_ws, size_t ws_size,
                              hipStream_t stream) {
    const float* hidden = (const float*)d_in[0];
    const int*   ids    = (const int*)d_in[1];
    const int*   amask  = (const int*)d_in[2];
    float*       out    = (float*)d_out;

    dim3 grid(B, 3);
    entity_pool_kernel<<<grid, 256, 0, stream>>>(hidden, ids, amask, out);
}